// Round 1
// baseline (586.642 us; speedup 1.0000x reference)
//
#include <hip/hip_runtime.h>

#define N_NODES 50000
#define E_EDGES 800000
#define EP (E_EDGES + N_NODES)   // edges + self loops = 850000
#define IN_CH 128
#define HID 64
#define HEADS 3
#define HC 192
#define OUT_CH 32
#define SLOPE 0.2f

// ---------------- edge sort (counting sort by dst) ----------------

__global__ void hist_kernel(const int* __restrict__ ei, int* __restrict__ cnt) {
    int i = blockIdx.x * 256 + threadIdx.x;
    if (i >= EP) return;
    int d = (i < E_EDGES) ? ei[E_EDGES + i] : (i - E_EDGES);
    atomicAdd(&cnt[d], 1);
}

// single-block work-efficient scan over N_NODES bins
__global__ void scan_kernel(const int* __restrict__ cnt, int* __restrict__ offs) {
    const int T = 1024;
    const int CH = (N_NODES + T - 1) / T;   // 49
    int t = threadIdx.x;
    int b0 = t * CH;
    int sum = 0;
    for (int j = 0; j < CH; ++j) { int i = b0 + j; if (i < N_NODES) sum += cnt[i]; }
    __shared__ int s[T];
    s[t] = sum; __syncthreads();
    for (int o = 1; o < T; o <<= 1) {
        int v = (t >= o) ? s[t - o] : 0;
        __syncthreads();
        s[t] += v;
        __syncthreads();
    }
    int run = s[t] - sum;                    // exclusive prefix of this chunk
    for (int j = 0; j < CH; ++j) {
        int i = b0 + j;
        if (i < N_NODES) { int v = cnt[i]; offs[i] = run; run += v; }
    }
    if (t == T - 1) offs[N_NODES] = s[T - 1];
}

__global__ void scatter_kernel(const int* __restrict__ ei, const int* __restrict__ offs,
                               int* __restrict__ cnt, int* __restrict__ src_sort,
                               int* __restrict__ pos) {
    int i = blockIdx.x * 256 + threadIdx.x;
    if (i >= EP) return;
    int s_, d_;
    if (i < E_EDGES) { s_ = ei[i]; d_ = ei[E_EDGES + i]; }
    else             { s_ = d_ = i - E_EDGES; }
    int slot = atomicAdd(&cnt[d_], 1);
    int p = offs[d_] + slot;
    src_sort[p] = s_;
    pos[i] = p;
}

// ---------------- fold MLP: Wf = Wf1@Wf2, bf = bf1@Wf2 + bf2 ----------------

__global__ void fold_kernel(const float* __restrict__ Wf1, const float* __restrict__ bf1,
                            const float* __restrict__ Wf2, const float* __restrict__ bf2,
                            float* __restrict__ Wf, float* __restrict__ bf) {
    int id = blockIdx.x * 256 + threadIdx.x;
    if (id < HC * OUT_CH) {
        int i = id / OUT_CH, j = id % OUT_CH;
        float s = 0.f;
        for (int k = 0; k < 64; ++k) s += Wf1[i * 64 + k] * Wf2[k * OUT_CH + j];
        Wf[id] = s;
    } else if (id < HC * OUT_CH + OUT_CH) {
        int j = id - HC * OUT_CH;
        float s = bf2[j];
        for (int k = 0; k < 64; ++k) s += bf1[k] * Wf2[k * OUT_CH + j];
        bf[j] = s;
    }
}

// ---------------- GEMM (M x K) @ (K x 192), fused alpha_src/alpha_dst ----------------
// block: 256 threads, tile BM=64 rows x BN=64 cols (one head), BK=32.

template <int K>
__global__ __launch_bounds__(256) void gemm_alpha_kernel(
    const float* __restrict__ X, const float* __restrict__ W,
    const float* __restrict__ a_src, const float* __restrict__ a_dst,
    float* __restrict__ Hout, float* __restrict__ AS, float* __restrict__ AD) {
    constexpr int BM = 64, BN = 64, BK = 32;
    __shared__ float As[BK][68];     // [k][m], padded for alignment/banks
    __shared__ float Bs[BK][BN];     // [k][n]
    int tid = threadIdx.x;
    int tx = tid & 15, ty = tid >> 4;
    int head = blockIdx.x;
    int n0 = head * BN;
    int m0 = blockIdx.y * BM;
    float acc[4][4] = {};

    for (int kb = 0; kb < K; kb += BK) {
        { // load X tile [64 rows][32 k], transpose into As
            int r = tid >> 2, kg = tid & 3;
            int row = m0 + r;
            float4 v0 = make_float4(0, 0, 0, 0), v1 = v0;
            if (row < N_NODES) {
                const float* xp = X + (size_t)row * K + kb + kg * 8;
                v0 = *(const float4*)xp;
                v1 = *(const float4*)(xp + 4);
            }
            int k0 = kg * 8;
            As[k0 + 0][r] = v0.x; As[k0 + 1][r] = v0.y; As[k0 + 2][r] = v0.z; As[k0 + 3][r] = v0.w;
            As[k0 + 4][r] = v1.x; As[k0 + 5][r] = v1.y; As[k0 + 6][r] = v1.z; As[k0 + 7][r] = v1.w;
        }
        { // load W tile [32 k][64 n]
            int kr = tid >> 3, ng = tid & 7;
            const float* wp = W + (size_t)(kb + kr) * HC + n0 + ng * 8;
            *(float4*)&Bs[kr][ng * 8]     = *(const float4*)wp;
            *(float4*)&Bs[kr][ng * 8 + 4] = *(const float4*)(wp + 4);
        }
        __syncthreads();
        #pragma unroll
        for (int k = 0; k < BK; ++k) {
            float4 a = *(const float4*)&As[k][ty * 4];
            float4 b = *(const float4*)&Bs[k][tx * 4];
            float av[4] = {a.x, a.y, a.z, a.w};
            float bv[4] = {b.x, b.y, b.z, b.w};
            #pragma unroll
            for (int r = 0; r < 4; ++r)
                #pragma unroll
                for (int c = 0; c < 4; ++c) acc[r][c] += av[r] * bv[c];
        }
        __syncthreads();
    }

    // store H tile
    #pragma unroll
    for (int r = 0; r < 4; ++r) {
        int row = m0 + ty * 4 + r;
        if (row < N_NODES) {
            float4 v = make_float4(acc[r][0], acc[r][1], acc[r][2], acc[r][3]);
            *(float4*)&Hout[(size_t)row * HC + n0 + tx * 4] = v;
        }
    }
    // fused alpha: reduce acc[r][:] * a_vec over the 64 cols of this head
    float4 as4 = *(const float4*)&a_src[head * HID + tx * 4];
    float4 ad4 = *(const float4*)&a_dst[head * HID + tx * 4];
    #pragma unroll
    for (int r = 0; r < 4; ++r) {
        float ps = acc[r][0] * as4.x + acc[r][1] * as4.y + acc[r][2] * as4.z + acc[r][3] * as4.w;
        float pd = acc[r][0] * ad4.x + acc[r][1] * ad4.y + acc[r][2] * ad4.z + acc[r][3] * ad4.w;
        #pragma unroll
        for (int o = 1; o < 16; o <<= 1) { ps += __shfl_xor(ps, o); pd += __shfl_xor(pd, o); }
        if (tx == 0) {
            int row = m0 + ty * 4 + r;
            if (row < N_NODES) { AS[row * 3 + head] = ps; AD[row * 3 + head] = pd; }
        }
    }
}

// ---------------- per-edge scores, written to dst-sorted positions ----------------

__global__ void edge_score_kernel(const int* __restrict__ ei, const float* __restrict__ AS,
                                  const float* __restrict__ AD, const int* __restrict__ pos,
                                  float* __restrict__ es) {
    int i = blockIdx.x * 256 + threadIdx.x;
    if (i >= EP) return;
    int s_, d_;
    if (i < E_EDGES) { s_ = ei[i]; d_ = ei[E_EDGES + i]; }
    else             { s_ = d_ = i - E_EDGES; }
    int p = pos[i];
    #pragma unroll
    for (int h = 0; h < 3; ++h) {
        float v = AS[s_ * 3 + h] + AD[d_ * 3 + h];
        v = (v > 0.f) ? v : SLOPE * v;
        es[p * 3 + h] = v;
    }
}

// ---------------- segment softmax + weighted scatter-sum, one wave per dst ----------------

__global__ __launch_bounds__(256) void aggregate_kernel(
    const float* __restrict__ es, const int* __restrict__ src_sort,
    const int* __restrict__ offs, const float* __restrict__ Hin,
    const float* __restrict__ bias, float* __restrict__ Aout) {
    int w = blockIdx.x * 4 + (threadIdx.x >> 6);
    if (w >= N_NODES) return;
    int lane = threadIdx.x & 63;
    int beg = offs[w], end = offs[w + 1];

    float m0 = -1e30f, m1 = -1e30f, m2 = -1e30f;
    for (int p = beg + lane; p < end; p += 64) {
        m0 = fmaxf(m0, es[p * 3 + 0]);
        m1 = fmaxf(m1, es[p * 3 + 1]);
        m2 = fmaxf(m2, es[p * 3 + 2]);
    }
    #pragma unroll
    for (int o = 1; o < 64; o <<= 1) {
        m0 = fmaxf(m0, __shfl_xor(m0, o));
        m1 = fmaxf(m1, __shfl_xor(m1, o));
        m2 = fmaxf(m2, __shfl_xor(m2, o));
    }
    float s0 = 0.f, s1 = 0.f, s2 = 0.f;
    for (int p = beg + lane; p < end; p += 64) {
        s0 += __expf(es[p * 3 + 0] - m0);
        s1 += __expf(es[p * 3 + 1] - m1);
        s2 += __expf(es[p * 3 + 2] - m2);
    }
    #pragma unroll
    for (int o = 1; o < 64; o <<= 1) {
        s0 += __shfl_xor(s0, o); s1 += __shfl_xor(s1, o); s2 += __shfl_xor(s2, o);
    }
    float i0 = 1.f / (s0 + 1e-16f), i1 = 1.f / (s1 + 1e-16f), i2 = 1.f / (s2 + 1e-16f);

    float a0 = 0.f, a1 = 0.f, a2 = 0.f;
    for (int p = beg; p < end; ++p) {
        int sn = src_sort[p];
        float w0 = __expf(es[p * 3 + 0] - m0) * i0;
        float w1 = __expf(es[p * 3 + 1] - m1) * i1;
        float w2 = __expf(es[p * 3 + 2] - m2) * i2;
        const float* hr = Hin + (size_t)sn * HC;
        a0 += w0 * hr[lane];
        a1 += w1 * hr[64 + lane];
        a2 += w2 * hr[128 + lane];
    }
    a0 += bias[lane];       a1 += bias[64 + lane];  a2 += bias[128 + lane];
    a0 = (a0 > 0.f) ? a0 : (__expf(a0) - 1.f);   // ELU
    a1 = (a1 > 0.f) ? a1 : (__expf(a1) - 1.f);
    a2 = (a2 > 0.f) ? a2 : (__expf(a2) - 1.f);
    float* op = Aout + (size_t)w * HC;
    op[lane] = a0; op[64 + lane] = a1; op[128 + lane] = a2;
}

// ---------------- final MLP: out = act @ Wf + bf ----------------

__global__ __launch_bounds__(256) void mlp_kernel(const float* __restrict__ act,
                                                  const float* __restrict__ Wf,
                                                  const float* __restrict__ bf,
                                                  float* __restrict__ out) {
    __shared__ float sW[HC * OUT_CH];       // 24 KB
    __shared__ float sA[32 * 193];          // 32 rows, padded stride (bank-friendly)
    __shared__ float sb[OUT_CH];
    int tid = threadIdx.x;
    for (int i = tid; i < HC * OUT_CH; i += 256) sW[i] = Wf[i];
    if (tid < OUT_CH) sb[tid] = bf[tid];
    int n0 = blockIdx.x * 32;
    for (int i = tid; i < 32 * HC; i += 256) {
        int r = i / HC, c = i % HC;
        int n = n0 + r;
        sA[r * 193 + c] = (n < N_NODES) ? act[(size_t)n * HC + c] : 0.f;
    }
    __syncthreads();
    int r = tid >> 3, jg = tid & 7;          // 32 rows x 8 col-groups(4)
    float a0 = sb[jg * 4 + 0], a1 = sb[jg * 4 + 1], a2 = sb[jg * 4 + 2], a3 = sb[jg * 4 + 3];
    #pragma unroll 4
    for (int k = 0; k < HC; ++k) {
        float xv = sA[r * 193 + k];
        float4 wv = *(const float4*)&sW[k * OUT_CH + jg * 4];
        a0 += xv * wv.x; a1 += xv * wv.y; a2 += xv * wv.z; a3 += xv * wv.w;
    }
    int n = n0 + r;
    if (n < N_NODES) {
        float4 v = make_float4(a0, a1, a2, a3);
        *(float4*)&out[(size_t)n * OUT_CH + jg * 4] = v;
    }
}

// ---------------- launch ----------------

extern "C" void kernel_launch(void* const* d_in, const int* in_sizes, int n_in,
                              void* d_out, int out_size, void* d_ws, size_t ws_size,
                              hipStream_t stream) {
    (void)in_sizes; (void)n_in; (void)out_size; (void)ws_size;
    const float* x   = (const float*)d_in[0];
    const int*   ei  = (const int*)d_in[1];
    const float* W1  = (const float*)d_in[2];
    const float* as1 = (const float*)d_in[3];
    const float* ad1 = (const float*)d_in[4];
    const float* b1  = (const float*)d_in[5];
    const float* W2  = (const float*)d_in[6];
    const float* as2 = (const float*)d_in[7];
    const float* ad2 = (const float*)d_in[8];
    const float* b2  = (const float*)d_in[9];
    const float* Wf1 = (const float*)d_in[10];
    const float* bf1 = (const float*)d_in[11];
    const float* Wf2 = (const float*)d_in[12];
    const float* bf2 = (const float*)d_in[13];
    float* out = (float*)d_out;

    char* ws = (char*)d_ws;
    size_t off = 0;
    auto alloc = [&](size_t b) { size_t o = off; off += (b + 255) & ~(size_t)255; return o; };
    float* A    = (float*)(ws + alloc((size_t)N_NODES * HC * 4));   // h
    float* B    = (float*)(ws + alloc((size_t)N_NODES * HC * 4));   // act
    float* ES   = (float*)(ws + alloc((size_t)EP * 3 * 4));         // sorted edge scores
    int*   POS  = (int*)  (ws + alloc((size_t)EP * 4));
    int*   SRC  = (int*)  (ws + alloc((size_t)EP * 4));
    float* AS   = (float*)(ws + alloc((size_t)N_NODES * 3 * 4));
    float* AD   = (float*)(ws + alloc((size_t)N_NODES * 3 * 4));
    int*   OFFS = (int*)  (ws + alloc((size_t)(N_NODES + 1) * 4));
    int*   CNT  = (int*)  (ws + alloc((size_t)N_NODES * 4));
    float* WF   = (float*)(ws + alloc((size_t)HC * OUT_CH * 4));
    float* BF   = (float*)(ws + alloc((size_t)OUT_CH * 4));

    int eb = (EP + 255) / 256;

    hipMemsetAsync(CNT, 0, (size_t)N_NODES * 4, stream);
    hist_kernel<<<eb, 256, 0, stream>>>(ei, CNT);
    scan_kernel<<<1, 1024, 0, stream>>>(CNT, OFFS);
    hipMemsetAsync(CNT, 0, (size_t)N_NODES * 4, stream);
    scatter_kernel<<<eb, 256, 0, stream>>>(ei, OFFS, CNT, SRC, POS);
    fold_kernel<<<(HC * OUT_CH + OUT_CH + 255) / 256, 256, 0, stream>>>(Wf1, bf1, Wf2, bf2, WF, BF);

    dim3 gg(HEADS, (N_NODES + 63) / 64);
    // layer 1
    gemm_alpha_kernel<IN_CH><<<gg, 256, 0, stream>>>(x, W1, as1, ad1, A, AS, AD);
    edge_score_kernel<<<eb, 256, 0, stream>>>(ei, AS, AD, POS, ES);
    aggregate_kernel<<<(N_NODES + 3) / 4, 256, 0, stream>>>(ES, SRC, OFFS, A, b1, B);
    // layer 2
    gemm_alpha_kernel<HC><<<gg, 256, 0, stream>>>(B, W2, as2, ad2, A, AS, AD);
    edge_score_kernel<<<eb, 256, 0, stream>>>(ei, AS, AD, POS, ES);
    aggregate_kernel<<<(N_NODES + 3) / 4, 256, 0, stream>>>(ES, SRC, OFFS, A, b2, B);
    // head
    mlp_kernel<<<(N_NODES + 31) / 32, 256, 0, stream>>>(B, WF, BF, out);
}

// Round 2
// 517.582 us; speedup vs baseline: 1.1334x; 1.1334x over previous
//
#include <hip/hip_runtime.h>

#define N_NODES 50000
#define E_EDGES 800000
#define EP (E_EDGES + N_NODES)   // edges + self loops = 850000
#define IN_CH 128
#define HID 64
#define HEADS 3
#define HC 192
#define OUT_CH 32
#define SLOPE 0.2f

__device__ __forceinline__ unsigned short f2bf(float f) {
    unsigned int u = __float_as_uint(f);
    u = (u + 0x7fffu + ((u >> 16) & 1u)) >> 16;   // round-to-nearest-even
    return (unsigned short)u;
}
__device__ __forceinline__ float bf2f(unsigned short u) {
    return __uint_as_float(((unsigned int)u) << 16);
}

// ---------------- edge sort (counting sort by dst) ----------------

__global__ void hist_kernel(const int* __restrict__ ei, int* __restrict__ cnt) {
    int i = blockIdx.x * 256 + threadIdx.x;
    if (i >= EP) return;
    int d = (i < E_EDGES) ? ei[E_EDGES + i] : (i - E_EDGES);
    atomicAdd(&cnt[d], 1);
}

// single-block work-efficient scan over N_NODES bins
__global__ void scan_kernel(const int* __restrict__ cnt, int* __restrict__ offs) {
    const int T = 1024;
    const int CH = (N_NODES + T - 1) / T;   // 49
    int t = threadIdx.x;
    int b0 = t * CH;
    int sum = 0;
    for (int j = 0; j < CH; ++j) { int i = b0 + j; if (i < N_NODES) sum += cnt[i]; }
    __shared__ int s[T];
    s[t] = sum; __syncthreads();
    for (int o = 1; o < T; o <<= 1) {
        int v = (t >= o) ? s[t - o] : 0;
        __syncthreads();
        s[t] += v;
        __syncthreads();
    }
    int run = s[t] - sum;                    // exclusive prefix of this chunk
    for (int j = 0; j < CH; ++j) {
        int i = b0 + j;
        if (i < N_NODES) { int v = cnt[i]; offs[i] = run; run += v; }
    }
    if (t == T - 1) offs[N_NODES] = s[T - 1];
}

__global__ void scatter_kernel(const int* __restrict__ ei, const int* __restrict__ offs,
                               int* __restrict__ cnt, int* __restrict__ src_sort,
                               int* __restrict__ dst_sort) {
    int i = blockIdx.x * 256 + threadIdx.x;
    if (i >= EP) return;
    int s_, d_;
    if (i < E_EDGES) { s_ = ei[i]; d_ = ei[E_EDGES + i]; }
    else             { s_ = d_ = i - E_EDGES; }
    int slot = atomicAdd(&cnt[d_], 1);
    int p = offs[d_] + slot;
    src_sort[p] = s_;
    dst_sort[p] = d_;
}

// ---------------- fold MLP: Wf = Wf1@Wf2, bf = bf1@Wf2 + bf2 ----------------

__global__ void fold_kernel(const float* __restrict__ Wf1, const float* __restrict__ bf1,
                            const float* __restrict__ Wf2, const float* __restrict__ bf2,
                            float* __restrict__ Wf, float* __restrict__ bf) {
    int id = blockIdx.x * 256 + threadIdx.x;
    if (id < HC * OUT_CH) {
        int i = id / OUT_CH, j = id % OUT_CH;
        float s = 0.f;
        for (int k = 0; k < 64; ++k) s += Wf1[i * 64 + k] * Wf2[k * OUT_CH + j];
        Wf[id] = s;
    } else if (id < HC * OUT_CH + OUT_CH) {
        int j = id - HC * OUT_CH;
        float s = bf2[j];
        for (int k = 0; k < 64; ++k) s += bf1[k] * Wf2[k * OUT_CH + j];
        bf[j] = s;
    }
}

// ---------------- GEMM (M x K) @ (K x 192), fused alpha_src/alpha_dst ----------------
// block: 256 threads, tile BM=64 rows x BN=64 cols (one head), BK=32.
// H output stored as bf16 (consumed only by the gather in aggregate_kernel).

template <int K>
__global__ __launch_bounds__(256) void gemm_alpha_kernel(
    const float* __restrict__ X, const float* __restrict__ W,
    const float* __restrict__ a_src, const float* __restrict__ a_dst,
    unsigned short* __restrict__ Hb, float* __restrict__ AS, float* __restrict__ AD) {
    constexpr int BM = 64, BN = 64, BK = 32;
    __shared__ float As[BK][68];     // [k][m], padded
    __shared__ float Bs[BK][BN];     // [k][n]
    int tid = threadIdx.x;
    int tx = tid & 15, ty = tid >> 4;
    int head = blockIdx.x;
    int n0 = head * BN;
    int m0 = blockIdx.y * BM;
    float acc[4][4] = {};

    for (int kb = 0; kb < K; kb += BK) {
        { // load X tile [64 rows][32 k], transpose into As
            int r = tid >> 2, kg = tid & 3;
            int row = m0 + r;
            float4 v0 = make_float4(0, 0, 0, 0), v1 = v0;
            if (row < N_NODES) {
                const float* xp = X + (size_t)row * K + kb + kg * 8;
                v0 = *(const float4*)xp;
                v1 = *(const float4*)(xp + 4);
            }
            int k0 = kg * 8;
            As[k0 + 0][r] = v0.x; As[k0 + 1][r] = v0.y; As[k0 + 2][r] = v0.z; As[k0 + 3][r] = v0.w;
            As[k0 + 4][r] = v1.x; As[k0 + 5][r] = v1.y; As[k0 + 6][r] = v1.z; As[k0 + 7][r] = v1.w;
        }
        { // load W tile [32 k][64 n]
            int kr = tid >> 3, ng = tid & 7;
            const float* wp = W + (size_t)(kb + kr) * HC + n0 + ng * 8;
            *(float4*)&Bs[kr][ng * 8]     = *(const float4*)wp;
            *(float4*)&Bs[kr][ng * 8 + 4] = *(const float4*)(wp + 4);
        }
        __syncthreads();
        #pragma unroll
        for (int k = 0; k < BK; ++k) {
            float4 a = *(const float4*)&As[k][ty * 4];
            float4 b = *(const float4*)&Bs[k][tx * 4];
            float av[4] = {a.x, a.y, a.z, a.w};
            float bv[4] = {b.x, b.y, b.z, b.w};
            #pragma unroll
            for (int r = 0; r < 4; ++r)
                #pragma unroll
                for (int c = 0; c < 4; ++c) acc[r][c] += av[r] * bv[c];
        }
        __syncthreads();
    }

    // store H tile as bf16 (packed 4 per row-chunk)
    #pragma unroll
    for (int r = 0; r < 4; ++r) {
        int row = m0 + ty * 4 + r;
        if (row < N_NODES) {
            uint2 v;
            v.x = (unsigned int)f2bf(acc[r][0]) | ((unsigned int)f2bf(acc[r][1]) << 16);
            v.y = (unsigned int)f2bf(acc[r][2]) | ((unsigned int)f2bf(acc[r][3]) << 16);
            *(uint2*)&Hb[(size_t)row * HC + n0 + tx * 4] = v;
        }
    }
    // fused alpha: reduce acc[r][:] * a_vec over the 64 cols of this head
    float4 as4 = *(const float4*)&a_src[head * HID + tx * 4];
    float4 ad4 = *(const float4*)&a_dst[head * HID + tx * 4];
    #pragma unroll
    for (int r = 0; r < 4; ++r) {
        float ps = acc[r][0] * as4.x + acc[r][1] * as4.y + acc[r][2] * as4.z + acc[r][3] * as4.w;
        float pd = acc[r][0] * ad4.x + acc[r][1] * ad4.y + acc[r][2] * ad4.z + acc[r][3] * ad4.w;
        #pragma unroll
        for (int o = 1; o < 16; o <<= 1) { ps += __shfl_xor(ps, o); pd += __shfl_xor(pd, o); }
        if (tx == 0) {
            int row = m0 + ty * 4 + r;
            if (row < N_NODES) { AS[row * 3 + head] = ps; AD[row * 3 + head] = pd; }
        }
    }
}

// ---------------- per-edge scores in sorted order (coalesced writes) ----------------

__global__ void edge_score_kernel(const int* __restrict__ src_sort, const int* __restrict__ dst_sort,
                                  const float* __restrict__ AS, const float* __restrict__ AD,
                                  float* __restrict__ es) {
    int p = blockIdx.x * 256 + threadIdx.x;
    if (p >= EP) return;
    int s_ = src_sort[p], d_ = dst_sort[p];
    #pragma unroll
    for (int h = 0; h < 3; ++h) {
        float v = AS[s_ * 3 + h] + AD[d_ * 3 + h];
        v = (v > 0.f) ? v : SLOPE * v;
        es[p * 3 + h] = v;
    }
}

// ---------------- segment softmax + weighted scatter-sum, one wave per dst ----------------

__global__ __launch_bounds__(256) void aggregate_kernel(
    const float* __restrict__ es, const int* __restrict__ src_sort,
    const int* __restrict__ offs, const unsigned short* __restrict__ Hb,
    const float* __restrict__ bias, float* __restrict__ Aout) {
    int w = blockIdx.x * 4 + (threadIdx.x >> 6);
    if (w >= N_NODES) return;
    int lane = threadIdx.x & 63;
    int beg = offs[w], end = offs[w + 1];

    float m0 = -1e30f, m1 = -1e30f, m2 = -1e30f;
    for (int p = beg + lane; p < end; p += 64) {
        m0 = fmaxf(m0, es[p * 3 + 0]);
        m1 = fmaxf(m1, es[p * 3 + 1]);
        m2 = fmaxf(m2, es[p * 3 + 2]);
    }
    #pragma unroll
    for (int o = 1; o < 64; o <<= 1) {
        m0 = fmaxf(m0, __shfl_xor(m0, o));
        m1 = fmaxf(m1, __shfl_xor(m1, o));
        m2 = fmaxf(m2, __shfl_xor(m2, o));
    }
    float s0 = 0.f, s1 = 0.f, s2 = 0.f;
    for (int p = beg + lane; p < end; p += 64) {
        s0 += __expf(es[p * 3 + 0] - m0);
        s1 += __expf(es[p * 3 + 1] - m1);
        s2 += __expf(es[p * 3 + 2] - m2);
    }
    #pragma unroll
    for (int o = 1; o < 64; o <<= 1) {
        s0 += __shfl_xor(s0, o); s1 += __shfl_xor(s1, o); s2 += __shfl_xor(s2, o);
    }
    float i0 = 1.f / (s0 + 1e-16f), i1 = 1.f / (s1 + 1e-16f), i2 = 1.f / (s2 + 1e-16f);

    // weighted gather-sum over bf16 rows, unrolled x2 with independent accumulators
    float a0 = 0.f, a1 = 0.f, a2 = 0.f;
    float b0 = 0.f, b1 = 0.f, b2 = 0.f;
    int p = beg;
    for (; p + 2 <= end; p += 2) {
        int sA = src_sort[p], sB = src_sort[p + 1];
        const unsigned short* rA = Hb + (size_t)sA * HC;
        const unsigned short* rB = Hb + (size_t)sB * HC;
        unsigned short uA0 = rA[lane], uA1 = rA[64 + lane], uA2 = rA[128 + lane];
        unsigned short uB0 = rB[lane], uB1 = rB[64 + lane], uB2 = rB[128 + lane];
        float wA0 = __expf(es[p * 3 + 0] - m0) * i0;
        float wA1 = __expf(es[p * 3 + 1] - m1) * i1;
        float wA2 = __expf(es[p * 3 + 2] - m2) * i2;
        float wB0 = __expf(es[p * 3 + 3] - m0) * i0;
        float wB1 = __expf(es[p * 3 + 4] - m1) * i1;
        float wB2 = __expf(es[p * 3 + 5] - m2) * i2;
        a0 += wA0 * bf2f(uA0); a1 += wA1 * bf2f(uA1); a2 += wA2 * bf2f(uA2);
        b0 += wB0 * bf2f(uB0); b1 += wB1 * bf2f(uB1); b2 += wB2 * bf2f(uB2);
    }
    if (p < end) {
        int sA = src_sort[p];
        const unsigned short* rA = Hb + (size_t)sA * HC;
        float wA0 = __expf(es[p * 3 + 0] - m0) * i0;
        float wA1 = __expf(es[p * 3 + 1] - m1) * i1;
        float wA2 = __expf(es[p * 3 + 2] - m2) * i2;
        a0 += wA0 * bf2f(rA[lane]);
        a1 += wA1 * bf2f(rA[64 + lane]);
        a2 += wA2 * bf2f(rA[128 + lane]);
    }
    a0 += b0; a1 += b1; a2 += b2;
    a0 += bias[lane];       a1 += bias[64 + lane];  a2 += bias[128 + lane];
    a0 = (a0 > 0.f) ? a0 : (__expf(a0) - 1.f);   // ELU
    a1 = (a1 > 0.f) ? a1 : (__expf(a1) - 1.f);
    a2 = (a2 > 0.f) ? a2 : (__expf(a2) - 1.f);
    float* op = Aout + (size_t)w * HC;
    op[lane] = a0; op[64 + lane] = a1; op[128 + lane] = a2;
}

// ---------------- final MLP: out = act @ Wf + bf ----------------

__global__ __launch_bounds__(256) void mlp_kernel(const float* __restrict__ act,
                                                  const float* __restrict__ Wf,
                                                  const float* __restrict__ bf,
                                                  float* __restrict__ out) {
    __shared__ float sW[HC * OUT_CH];       // 24 KB
    __shared__ float sA[32 * 193];          // 32 rows, padded stride
    __shared__ float sb[OUT_CH];
    int tid = threadIdx.x;
    for (int i = tid; i < HC * OUT_CH; i += 256) sW[i] = Wf[i];
    if (tid < OUT_CH) sb[tid] = bf[tid];
    int n0 = blockIdx.x * 32;
    for (int i = tid; i < 32 * HC; i += 256) {
        int r = i / HC, c = i % HC;
        int n = n0 + r;
        sA[r * 193 + c] = (n < N_NODES) ? act[(size_t)n * HC + c] : 0.f;
    }
    __syncthreads();
    int r = tid >> 3, jg = tid & 7;          // 32 rows x 8 col-groups(4)
    float a0 = sb[jg * 4 + 0], a1 = sb[jg * 4 + 1], a2 = sb[jg * 4 + 2], a3 = sb[jg * 4 + 3];
    #pragma unroll 4
    for (int k = 0; k < HC; ++k) {
        float xv = sA[r * 193 + k];
        float4 wv = *(const float4*)&sW[k * OUT_CH + jg * 4];
        a0 += xv * wv.x; a1 += xv * wv.y; a2 += xv * wv.z; a3 += xv * wv.w;
    }
    int n = n0 + r;
    if (n < N_NODES) {
        float4 v = make_float4(a0, a1, a2, a3);
        *(float4*)&out[(size_t)n * OUT_CH + jg * 4] = v;
    }
}

// ---------------- launch ----------------

extern "C" void kernel_launch(void* const* d_in, const int* in_sizes, int n_in,
                              void* d_out, int out_size, void* d_ws, size_t ws_size,
                              hipStream_t stream) {
    (void)in_sizes; (void)n_in; (void)out_size; (void)ws_size;
    const float* x   = (const float*)d_in[0];
    const int*   ei  = (const int*)d_in[1];
    const float* W1  = (const float*)d_in[2];
    const float* as1 = (const float*)d_in[3];
    const float* ad1 = (const float*)d_in[4];
    const float* b1  = (const float*)d_in[5];
    const float* W2  = (const float*)d_in[6];
    const float* as2 = (const float*)d_in[7];
    const float* ad2 = (const float*)d_in[8];
    const float* b2  = (const float*)d_in[9];
    const float* Wf1 = (const float*)d_in[10];
    const float* bf1 = (const float*)d_in[11];
    const float* Wf2 = (const float*)d_in[12];
    const float* bf2 = (const float*)d_in[13];
    float* out = (float*)d_out;

    char* ws = (char*)d_ws;
    size_t off = 0;
    auto alloc = [&](size_t b) { size_t o = off; off += (b + 255) & ~(size_t)255; return o; };
    unsigned short* HB = (unsigned short*)(ws + alloc((size_t)N_NODES * HC * 2)); // h (bf16)
    float* B    = (float*)(ws + alloc((size_t)N_NODES * HC * 4));   // act (fp32)
    float* ES   = (float*)(ws + alloc((size_t)EP * 3 * 4));         // sorted edge scores
    int*   SRC  = (int*)  (ws + alloc((size_t)EP * 4));
    int*   DST  = (int*)  (ws + alloc((size_t)EP * 4));
    float* AS   = (float*)(ws + alloc((size_t)N_NODES * 3 * 4));
    float* AD   = (float*)(ws + alloc((size_t)N_NODES * 3 * 4));
    int*   OFFS = (int*)  (ws + alloc((size_t)(N_NODES + 1) * 4));
    int*   CNT  = (int*)  (ws + alloc((size_t)N_NODES * 4));
    float* WF   = (float*)(ws + alloc((size_t)HC * OUT_CH * 4));
    float* BF   = (float*)(ws + alloc((size_t)OUT_CH * 4));

    int eb = (EP + 255) / 256;

    hipMemsetAsync(CNT, 0, (size_t)N_NODES * 4, stream);
    hist_kernel<<<eb, 256, 0, stream>>>(ei, CNT);
    scan_kernel<<<1, 1024, 0, stream>>>(CNT, OFFS);
    hipMemsetAsync(CNT, 0, (size_t)N_NODES * 4, stream);
    scatter_kernel<<<eb, 256, 0, stream>>>(ei, OFFS, CNT, SRC, DST);
    fold_kernel<<<(HC * OUT_CH + OUT_CH + 255) / 256, 256, 0, stream>>>(Wf1, bf1, Wf2, bf2, WF, BF);

    dim3 gg(HEADS, (N_NODES + 63) / 64);
    // layer 1
    gemm_alpha_kernel<IN_CH><<<gg, 256, 0, stream>>>(x, W1, as1, ad1, HB, AS, AD);
    edge_score_kernel<<<eb, 256, 0, stream>>>(SRC, DST, AS, AD, ES);
    aggregate_kernel<<<(N_NODES + 3) / 4, 256, 0, stream>>>(ES, SRC, OFFS, HB, b1, B);
    // layer 2
    gemm_alpha_kernel<HC><<<gg, 256, 0, stream>>>(B, W2, as2, ad2, HB, AS, AD);
    edge_score_kernel<<<eb, 256, 0, stream>>>(SRC, DST, AS, AD, ES);
    aggregate_kernel<<<(N_NODES + 3) / 4, 256, 0, stream>>>(ES, SRC, OFFS, HB, b2, B);
    // head
    mlp_kernel<<<(N_NODES + 31) / 32, 256, 0, stream>>>(B, WF, BF, out);
}

// Round 3
// 424.092 us; speedup vs baseline: 1.3833x; 1.2204x over previous
//
#include <hip/hip_runtime.h>

#define N_NODES 50000
#define E_EDGES 800000
#define EP (E_EDGES + N_NODES)   // edges + self loops = 850000
#define IN_CH 128
#define HID 64
#define HEADS 3
#define HC 192
#define OUT_CH 32
#define SLOPE 0.2f

#define N4 12500                 // N_NODES / 4 (exact)
#define SCAN_BLK 49              // ceil(N4 / 256)

__device__ __forceinline__ unsigned short f2bf(float f) {
    unsigned int u = __float_as_uint(f);
    u = (u + 0x7fffu + ((u >> 16) & 1u)) >> 16;   // round-to-nearest-even
    return (unsigned short)u;
}
__device__ __forceinline__ float bf2f(unsigned short u) {
    return __uint_as_float(((unsigned int)u) << 16);
}

// ---------------- edge sort (counting sort by dst) ----------------

__global__ void hist_kernel(const int* __restrict__ ei, int* __restrict__ cnt) {
    int i = blockIdx.x * 256 + threadIdx.x;
    if (i >= EP) return;
    int d = (i < E_EDGES) ? ei[E_EDGES + i] : (i - E_EDGES);
    atomicAdd(&cnt[d], 1);
}

// ---- 3-phase hierarchical exclusive scan over N_NODES bins ----

// A: block-local scan, 4 bins/thread (int4), 256 threads -> 1024 bins/block
__global__ __launch_bounds__(256) void scan_local_kernel(const int* __restrict__ cnt,
                                                         int* __restrict__ offs,
                                                         int* __restrict__ bsum) {
    __shared__ int s[256];
    int t = threadIdx.x;
    int g = blockIdx.x * 256 + t;          // int4 index
    int4 v = make_int4(0, 0, 0, 0);
    if (g < N4) v = ((const int4*)cnt)[g];
    int sum = v.x + v.y + v.z + v.w;
    s[t] = sum; __syncthreads();
    #pragma unroll
    for (int o = 1; o < 256; o <<= 1) {
        int u = (t >= o) ? s[t - o] : 0;
        __syncthreads();
        s[t] += u;
        __syncthreads();
    }
    int ex = s[t] - sum;                   // exclusive prefix within block
    if (g < N4) {
        int4 w;
        w.x = ex;
        w.y = ex + v.x;
        w.z = ex + v.x + v.y;
        w.w = ex + v.x + v.y + v.z;
        ((int4*)offs)[g] = w;
    }
    if (t == 255) bsum[blockIdx.x] = s[255];
}

// B: one wave scans the SCAN_BLK block sums; writes grand total to offs[N]
__global__ void scan_bsum_kernel(int* __restrict__ bsum, int* __restrict__ offs) {
    int t = threadIdx.x;                   // 64 threads, single wave
    int orig = (t < SCAN_BLK) ? bsum[t] : 0;
    int v = orig;
    #pragma unroll
    for (int o = 1; o < 64; o <<= 1) {
        int u = __shfl_up(v, o);
        if (t >= o) v += u;
    }
    if (t < SCAN_BLK) bsum[t] = v - orig;  // exclusive block offset
    if (t == SCAN_BLK - 1) offs[N_NODES] = v;
}

// C: add block offsets
__global__ __launch_bounds__(256) void scan_add_kernel(int* __restrict__ offs,
                                                       const int* __restrict__ bsum) {
    int g = blockIdx.x * 256 + threadIdx.x;
    int add = bsum[blockIdx.x];
    if (g < N4) {
        int4 w = ((int4*)offs)[g];
        w.x += add; w.y += add; w.z += add; w.w += add;
        ((int4*)offs)[g] = w;
    }
}

__global__ void scatter_kernel(const int* __restrict__ ei, const int* __restrict__ offs,
                               int* __restrict__ cnt, int* __restrict__ src_sort,
                               int* __restrict__ dst_sort) {
    int i = blockIdx.x * 256 + threadIdx.x;
    if (i >= EP) return;
    int s_, d_;
    if (i < E_EDGES) { s_ = ei[i]; d_ = ei[E_EDGES + i]; }
    else             { s_ = d_ = i - E_EDGES; }
    int slot = atomicAdd(&cnt[d_], 1);
    int p = offs[d_] + slot;
    src_sort[p] = s_;
    dst_sort[p] = d_;
}

// ---------------- fold MLP: Wf = Wf1@Wf2, bf = bf1@Wf2 + bf2 ----------------

__global__ void fold_kernel(const float* __restrict__ Wf1, const float* __restrict__ bf1,
                            const float* __restrict__ Wf2, const float* __restrict__ bf2,
                            float* __restrict__ Wf, float* __restrict__ bf) {
    int id = blockIdx.x * 256 + threadIdx.x;
    if (id < HC * OUT_CH) {
        int i = id / OUT_CH, j = id % OUT_CH;
        float s = 0.f;
        for (int k = 0; k < 64; ++k) s += Wf1[i * 64 + k] * Wf2[k * OUT_CH + j];
        Wf[id] = s;
    } else if (id < HC * OUT_CH + OUT_CH) {
        int j = id - HC * OUT_CH;
        float s = bf2[j];
        for (int k = 0; k < 64; ++k) s += bf1[k] * Wf2[k * OUT_CH + j];
        bf[j] = s;
    }
}

// ---------------- GEMM (M x K) @ (K x 192), fused alpha_src/alpha_dst ----------------

template <int K>
__global__ __launch_bounds__(256) void gemm_alpha_kernel(
    const float* __restrict__ X, const float* __restrict__ W,
    const float* __restrict__ a_src, const float* __restrict__ a_dst,
    unsigned short* __restrict__ Hb, float* __restrict__ AS, float* __restrict__ AD) {
    constexpr int BM = 64, BN = 64, BK = 32;
    __shared__ float As[BK][68];     // [k][m], padded
    __shared__ float Bs[BK][BN];     // [k][n]
    int tid = threadIdx.x;
    int tx = tid & 15, ty = tid >> 4;
    int head = blockIdx.x;
    int n0 = head * BN;
    int m0 = blockIdx.y * BM;
    float acc[4][4] = {};

    for (int kb = 0; kb < K; kb += BK) {
        { // load X tile [64 rows][32 k], transpose into As
            int r = tid >> 2, kg = tid & 3;
            int row = m0 + r;
            float4 v0 = make_float4(0, 0, 0, 0), v1 = v0;
            if (row < N_NODES) {
                const float* xp = X + (size_t)row * K + kb + kg * 8;
                v0 = *(const float4*)xp;
                v1 = *(const float4*)(xp + 4);
            }
            int k0 = kg * 8;
            As[k0 + 0][r] = v0.x; As[k0 + 1][r] = v0.y; As[k0 + 2][r] = v0.z; As[k0 + 3][r] = v0.w;
            As[k0 + 4][r] = v1.x; As[k0 + 5][r] = v1.y; As[k0 + 6][r] = v1.z; As[k0 + 7][r] = v1.w;
        }
        { // load W tile [32 k][64 n]
            int kr = tid >> 3, ng = tid & 7;
            const float* wp = W + (size_t)(kb + kr) * HC + n0 + ng * 8;
            *(float4*)&Bs[kr][ng * 8]     = *(const float4*)wp;
            *(float4*)&Bs[kr][ng * 8 + 4] = *(const float4*)(wp + 4);
        }
        __syncthreads();
        #pragma unroll
        for (int k = 0; k < BK; ++k) {
            float4 a = *(const float4*)&As[k][ty * 4];
            float4 b = *(const float4*)&Bs[k][tx * 4];
            float av[4] = {a.x, a.y, a.z, a.w};
            float bv[4] = {b.x, b.y, b.z, b.w};
            #pragma unroll
            for (int r = 0; r < 4; ++r)
                #pragma unroll
                for (int c = 0; c < 4; ++c) acc[r][c] += av[r] * bv[c];
        }
        __syncthreads();
    }

    // store H tile as bf16
    #pragma unroll
    for (int r = 0; r < 4; ++r) {
        int row = m0 + ty * 4 + r;
        if (row < N_NODES) {
            uint2 v;
            v.x = (unsigned int)f2bf(acc[r][0]) | ((unsigned int)f2bf(acc[r][1]) << 16);
            v.y = (unsigned int)f2bf(acc[r][2]) | ((unsigned int)f2bf(acc[r][3]) << 16);
            *(uint2*)&Hb[(size_t)row * HC + n0 + tx * 4] = v;
        }
    }
    // fused alpha
    float4 as4 = *(const float4*)&a_src[head * HID + tx * 4];
    float4 ad4 = *(const float4*)&a_dst[head * HID + tx * 4];
    #pragma unroll
    for (int r = 0; r < 4; ++r) {
        float ps = acc[r][0] * as4.x + acc[r][1] * as4.y + acc[r][2] * as4.z + acc[r][3] * as4.w;
        float pd = acc[r][0] * ad4.x + acc[r][1] * ad4.y + acc[r][2] * ad4.z + acc[r][3] * ad4.w;
        #pragma unroll
        for (int o = 1; o < 16; o <<= 1) { ps += __shfl_xor(ps, o); pd += __shfl_xor(pd, o); }
        if (tx == 0) {
            int row = m0 + ty * 4 + r;
            if (row < N_NODES) { AS[row * 3 + head] = ps; AD[row * 3 + head] = pd; }
        }
    }
}

// ---------------- per-edge scores in sorted order ----------------

__global__ void edge_score_kernel(const int* __restrict__ src_sort, const int* __restrict__ dst_sort,
                                  const float* __restrict__ AS, const float* __restrict__ AD,
                                  float* __restrict__ es) {
    int p = blockIdx.x * 256 + threadIdx.x;
    if (p >= EP) return;
    int s_ = src_sort[p], d_ = dst_sort[p];
    #pragma unroll
    for (int h = 0; h < 3; ++h) {
        float v = AS[s_ * 3 + h] + AD[d_ * 3 + h];
        v = (v > 0.f) ? v : SLOPE * v;
        es[p * 3 + h] = v;
    }
}

// ---------------- segment softmax + weighted gather-sum, one wave per dst ----------------
// Deferred normalization: accumulate unnormalized exp-weighted sum + denominator in one pass.

__global__ __launch_bounds__(256) void aggregate_kernel(
    const float* __restrict__ es, const int* __restrict__ src_sort,
    const int* __restrict__ offs, const unsigned short* __restrict__ Hb,
    const float* __restrict__ bias, float* __restrict__ Aout) {
    int w = blockIdx.x * 4 + (threadIdx.x >> 6);
    if (w >= N_NODES) return;
    int lane = threadIdx.x & 63;
    int beg = offs[w], end = offs[w + 1];

    // pass 1: per-head max (lane-parallel, strided)
    float m0 = -1e30f, m1 = -1e30f, m2 = -1e30f;
    for (int p = beg + lane; p < end; p += 64) {
        m0 = fmaxf(m0, es[p * 3 + 0]);
        m1 = fmaxf(m1, es[p * 3 + 1]);
        m2 = fmaxf(m2, es[p * 3 + 2]);
    }
    #pragma unroll
    for (int o = 1; o < 64; o <<= 1) {
        m0 = fmaxf(m0, __shfl_xor(m0, o));
        m1 = fmaxf(m1, __shfl_xor(m1, o));
        m2 = fmaxf(m2, __shfl_xor(m2, o));
    }

    // pass 2: unnormalized weighted gather + denominator, unrolled x2
    float a0 = 0.f, a1 = 0.f, a2 = 0.f, sA0 = 0.f, sA1 = 0.f, sA2 = 0.f;
    float b0 = 0.f, b1 = 0.f, b2 = 0.f, sB0 = 0.f, sB1 = 0.f, sB2 = 0.f;
    int p = beg;
    for (; p + 2 <= end; p += 2) {
        int nA = src_sort[p], nB = src_sort[p + 1];
        const unsigned short* rA = Hb + (size_t)nA * HC;
        const unsigned short* rB = Hb + (size_t)nB * HC;
        unsigned short uA0 = rA[lane], uA1 = rA[64 + lane], uA2 = rA[128 + lane];
        unsigned short uB0 = rB[lane], uB1 = rB[64 + lane], uB2 = rB[128 + lane];
        float wA0 = __expf(es[p * 3 + 0] - m0);
        float wA1 = __expf(es[p * 3 + 1] - m1);
        float wA2 = __expf(es[p * 3 + 2] - m2);
        float wB0 = __expf(es[p * 3 + 3] - m0);
        float wB1 = __expf(es[p * 3 + 4] - m1);
        float wB2 = __expf(es[p * 3 + 5] - m2);
        sA0 += wA0; sA1 += wA1; sA2 += wA2;
        sB0 += wB0; sB1 += wB1; sB2 += wB2;
        a0 += wA0 * bf2f(uA0); a1 += wA1 * bf2f(uA1); a2 += wA2 * bf2f(uA2);
        b0 += wB0 * bf2f(uB0); b1 += wB1 * bf2f(uB1); b2 += wB2 * bf2f(uB2);
    }
    if (p < end) {
        int nA = src_sort[p];
        const unsigned short* rA = Hb + (size_t)nA * HC;
        float wA0 = __expf(es[p * 3 + 0] - m0);
        float wA1 = __expf(es[p * 3 + 1] - m1);
        float wA2 = __expf(es[p * 3 + 2] - m2);
        sA0 += wA0; sA1 += wA1; sA2 += wA2;
        a0 += wA0 * bf2f(rA[lane]);
        a1 += wA1 * bf2f(rA[64 + lane]);
        a2 += wA2 * bf2f(rA[128 + lane]);
    }
    a0 += b0; a1 += b1; a2 += b2;
    float i0 = 1.f / (sA0 + sB0 + 1e-16f);
    float i1 = 1.f / (sA1 + sB1 + 1e-16f);
    float i2 = 1.f / (sA2 + sB2 + 1e-16f);
    a0 = a0 * i0 + bias[lane];
    a1 = a1 * i1 + bias[64 + lane];
    a2 = a2 * i2 + bias[128 + lane];
    a0 = (a0 > 0.f) ? a0 : (__expf(a0) - 1.f);   // ELU
    a1 = (a1 > 0.f) ? a1 : (__expf(a1) - 1.f);
    a2 = (a2 > 0.f) ? a2 : (__expf(a2) - 1.f);
    float* op = Aout + (size_t)w * HC;
    op[lane] = a0; op[64 + lane] = a1; op[128 + lane] = a2;
}

// ---------------- final MLP: out = act @ Wf + bf ----------------

__global__ __launch_bounds__(256) void mlp_kernel(const float* __restrict__ act,
                                                  const float* __restrict__ Wf,
                                                  const float* __restrict__ bf,
                                                  float* __restrict__ out) {
    __shared__ float sW[HC * OUT_CH];       // 24 KB
    __shared__ float sA[32 * 193];
    __shared__ float sb[OUT_CH];
    int tid = threadIdx.x;
    for (int i = tid; i < HC * OUT_CH; i += 256) sW[i] = Wf[i];
    if (tid < OUT_CH) sb[tid] = bf[tid];
    int n0 = blockIdx.x * 32;
    for (int i = tid; i < 32 * HC; i += 256) {
        int r = i / HC, c = i % HC;
        int n = n0 + r;
        sA[r * 193 + c] = (n < N_NODES) ? act[(size_t)n * HC + c] : 0.f;
    }
    __syncthreads();
    int r = tid >> 3, jg = tid & 7;
    float a0 = sb[jg * 4 + 0], a1 = sb[jg * 4 + 1], a2 = sb[jg * 4 + 2], a3 = sb[jg * 4 + 3];
    #pragma unroll 4
    for (int k = 0; k < HC; ++k) {
        float xv = sA[r * 193 + k];
        float4 wv = *(const float4*)&sW[k * OUT_CH + jg * 4];
        a0 += xv * wv.x; a1 += xv * wv.y; a2 += xv * wv.z; a3 += xv * wv.w;
    }
    int n = n0 + r;
    if (n < N_NODES) {
        float4 v = make_float4(a0, a1, a2, a3);
        *(float4*)&out[(size_t)n * OUT_CH + jg * 4] = v;
    }
}

// ---------------- launch ----------------

extern "C" void kernel_launch(void* const* d_in, const int* in_sizes, int n_in,
                              void* d_out, int out_size, void* d_ws, size_t ws_size,
                              hipStream_t stream) {
    (void)in_sizes; (void)n_in; (void)out_size; (void)ws_size;
    const float* x   = (const float*)d_in[0];
    const int*   ei  = (const int*)d_in[1];
    const float* W1  = (const float*)d_in[2];
    const float* as1 = (const float*)d_in[3];
    const float* ad1 = (const float*)d_in[4];
    const float* b1  = (const float*)d_in[5];
    const float* W2  = (const float*)d_in[6];
    const float* as2 = (const float*)d_in[7];
    const float* ad2 = (const float*)d_in[8];
    const float* b2  = (const float*)d_in[9];
    const float* Wf1 = (const float*)d_in[10];
    const float* bf1 = (const float*)d_in[11];
    const float* Wf2 = (const float*)d_in[12];
    const float* bf2 = (const float*)d_in[13];
    float* out = (float*)d_out;

    char* ws = (char*)d_ws;
    size_t off = 0;
    auto alloc = [&](size_t b) { size_t o = off; off += (b + 255) & ~(size_t)255; return o; };
    unsigned short* HB = (unsigned short*)(ws + alloc((size_t)N_NODES * HC * 2)); // h (bf16)
    float* B    = (float*)(ws + alloc((size_t)N_NODES * HC * 4));   // act (fp32)
    float* ES   = (float*)(ws + alloc((size_t)EP * 3 * 4));         // sorted edge scores
    int*   SRC  = (int*)  (ws + alloc((size_t)EP * 4));
    int*   DST  = (int*)  (ws + alloc((size_t)EP * 4));
    float* AS   = (float*)(ws + alloc((size_t)N_NODES * 3 * 4));
    float* AD   = (float*)(ws + alloc((size_t)N_NODES * 3 * 4));
    int*   OFFS = (int*)  (ws + alloc((size_t)(N_NODES + 4) * 4));
    int*   CNT  = (int*)  (ws + alloc((size_t)N_NODES * 4));
    int*   BSUM = (int*)  (ws + alloc((size_t)256 * 4));
    float* WF   = (float*)(ws + alloc((size_t)HC * OUT_CH * 4));
    float* BF   = (float*)(ws + alloc((size_t)OUT_CH * 4));

    int eb = (EP + 255) / 256;

    hipMemsetAsync(CNT, 0, (size_t)N_NODES * 4, stream);
    hist_kernel<<<eb, 256, 0, stream>>>(ei, CNT);
    scan_local_kernel<<<SCAN_BLK, 256, 0, stream>>>(CNT, OFFS, BSUM);
    scan_bsum_kernel<<<1, 64, 0, stream>>>(BSUM, OFFS);
    scan_add_kernel<<<SCAN_BLK, 256, 0, stream>>>(OFFS, BSUM);
    hipMemsetAsync(CNT, 0, (size_t)N_NODES * 4, stream);
    scatter_kernel<<<eb, 256, 0, stream>>>(ei, OFFS, CNT, SRC, DST);
    fold_kernel<<<(HC * OUT_CH + OUT_CH + 255) / 256, 256, 0, stream>>>(Wf1, bf1, Wf2, bf2, WF, BF);

    dim3 gg(HEADS, (N_NODES + 63) / 64);
    // layer 1
    gemm_alpha_kernel<IN_CH><<<gg, 256, 0, stream>>>(x, W1, as1, ad1, HB, AS, AD);
    edge_score_kernel<<<eb, 256, 0, stream>>>(SRC, DST, AS, AD, ES);
    aggregate_kernel<<<(N_NODES + 3) / 4, 256, 0, stream>>>(ES, SRC, OFFS, HB, b1, B);
    // layer 2
    gemm_alpha_kernel<HC><<<gg, 256, 0, stream>>>(B, W2, as2, ad2, HB, AS, AD);
    edge_score_kernel<<<eb, 256, 0, stream>>>(SRC, DST, AS, AD, ES);
    aggregate_kernel<<<(N_NODES + 3) / 4, 256, 0, stream>>>(ES, SRC, OFFS, HB, b2, B);
    // head
    mlp_kernel<<<(N_NODES + 31) / 32, 256, 0, stream>>>(B, WF, BF, out);
}